// Round 25
// baseline (215.165 us; speedup 1.0000x reference)
//
#include <hip/hip_runtime.h>

typedef __attribute__((ext_vector_type(8))) short bf16x8;
typedef __attribute__((ext_vector_type(4))) float f32x4;
typedef __attribute__((ext_vector_type(4))) short s16x4;
using u16 = unsigned short;
using u8 = unsigned char;

#define DEVINL static __device__ __forceinline__

DEVINL u16 f2bf(float f) {
  union { float f; unsigned u; } v; v.f = f;
  unsigned r = v.u + 0x7FFFu + ((v.u >> 16) & 1u);   // RNE
  return (u16)(r >> 16);
}

// fp32 -> OCP e4m3fn. Software fallback (RNE, saturating, denormal-aware).
DEVINL u8 f2e4m3_sw(float f) {
  union { float f; unsigned u; } v; v.f = f;
  unsigned s = (v.u >> 24) & 0x80u;
  float a = fabsf(f);
  a = fminf(a, 448.f);
  union { float f; unsigned u; } b; b.f = a;
  unsigned bu = b.u + 0x7FFFFu + ((b.u >> 20) & 1u);   // RNE at bit 20
  unsigned e = bu >> 23;
  unsigned r;
  if (e >= 121) {
    r = ((e - 120) << 3) | ((bu >> 20) & 7u);
    if (r > 0x7Eu) r = 0x7Eu;
  } else {
    r = (unsigned)(a * 512.f + 0.5f);
    if (r > 7u) r = 8u;
  }
  return (u8)(r | s);
}

#if __has_builtin(__builtin_amdgcn_cvt_pk_fp8_f32)
DEVINL u8 f2e4m3(float f) {
  int p = __builtin_amdgcn_cvt_pk_fp8_f32(f, f, 0, false);
  return (u8)(p & 0xFF);
}
#else
DEVINL u8 f2e4m3(float f) { return f2e4m3_sw(f); }
#endif

DEVINL float bf2f(u16 h) {
  union { unsigned u; float f; } v; v.u = ((unsigned)h) << 16; return v.f;
}

DEVINL void gload16(const u16* g, u16* l) {
  __builtin_amdgcn_global_load_lds((const __attribute__((address_space(1))) void*)g,
                                   (__attribute__((address_space(3))) void*)l,
                                   16, 0, 0);
}
DEVINL void gload16b(const u8* g, u8* l) {
  __builtin_amdgcn_global_load_lds((const __attribute__((address_space(1))) void*)g,
                                   (__attribute__((address_space(3))) void*)l,
                                   16, 0, 0);
}

// ---------------- GroupNorm stats: two-stage, 512-block parallel ----------------
__global__ __launch_bounds__(256) void gn_stats1_k(const float* __restrict__ x,
                                                   float* __restrict__ psum,
                                                   float* __restrict__ psumsq) {
  const int blk = blockIdx.x;
  const float4* p4 = (const float4*)(x + (size_t)(blk >> 4) * (64 * 4096))
                     + (size_t)(blk & 15) * 4096;
  float s = 0.f, ss = 0.f;
  #pragma unroll
  for (int i = 0; i < 16; ++i) {
    float4 v = p4[i*256 + threadIdx.x];
    s  += v.x + v.y + v.z + v.w;
    ss += v.x*v.x + v.y*v.y + v.z*v.z + v.w*v.w;
  }
  #pragma unroll
  for (int off = 32; off > 0; off >>= 1) {
    s  += __shfl_down(s, off, 64);
    ss += __shfl_down(ss, off, 64);
  }
  __shared__ float rs[4], rss[4];
  const int lane = threadIdx.x & 63, w = threadIdx.x >> 6;
  if (lane == 0) { rs[w] = s; rss[w] = ss; }
  __syncthreads();
  if (threadIdx.x == 0) {
    psum[blk]   = rs[0]+rs[1]+rs[2]+rs[3];
    psumsq[blk] = rss[0]+rss[1]+rss[2]+rss[3];
  }
}

__global__ void gn_stats2_k(const float* __restrict__ psum,
                            const float* __restrict__ psumsq,
                            float* __restrict__ stats) {
  const int bg = threadIdx.x;   // 32 threads
  if (bg >= 32) return;
  float s = 0.f, ss = 0.f;
  #pragma unroll
  for (int p = 0; p < 16; ++p) { s += psum[bg*16+p]; ss += psumsq[bg*16+p]; }
  const float inv = 1.f / 262144.f;
  float mean = s * inv;
  float var  = ss * inv - mean * mean;
  stats[bg*2]   = mean;
  stats[bg*2+1] = rsqrtf(var + 1e-5f);
}

// Normalize + transpose: x[b][c][n] -> hT[b][n][c]. fp8 when useF8, else bf16.
__global__ __launch_bounds__(256) void gn_apply_k(const float* __restrict__ x,
                                                  const float* __restrict__ gamma,
                                                  const float* __restrict__ beta,
                                                  const float* __restrict__ stats,
                                                  u16* __restrict__ hT,
                                                  u8* __restrict__ hT8, int useF8) {
  __shared__ u16 tile[64][68];
  const int b = blockIdx.z, ct = blockIdx.y, nt = blockIdx.x;
  const int t = threadIdx.x;
  const float mean = stats[(b*8 + ct)*2 + 0];
  const float rstd = stats[(b*8 + ct)*2 + 1];
  const float* xb = x + ((size_t)b*512 + (size_t)ct*64) * 4096 + nt*64;
  #pragma unroll
  for (int i = 0; i < 4; ++i) {
    int idx = i*256 + t;                 // 1024 float4 loads cover 64x64
    int cl = idx >> 4, nl4 = idx & 15;
    float4 v = *(const float4*)(xb + (size_t)cl*4096 + nl4*4);
    float g = gamma[ct*64 + cl], bb = beta[ct*64 + cl];
    s16x4 o;
    o.x = (short)f2bf((v.x - mean) * rstd * g + bb);
    o.y = (short)f2bf((v.y - mean) * rstd * g + bb);
    o.z = (short)f2bf((v.z - mean) * rstd * g + bb);
    o.w = (short)f2bf((v.w - mean) * rstd * g + bb);
    *(s16x4*)(&tile[cl][nl4*4]) = o;
  }
  __syncthreads();
  if (useF8) {
    u8* o = hT8 + ((size_t)b*4096 + (size_t)nt*64) * 512 + ct*64;
    #pragma unroll
    for (int i = 0; i < 16; ++i) {
      int idx = i*256 + t; int nl = idx >> 6, cl = idx & 63;
      o[(size_t)nl*512 + cl] = f2e4m3(bf2f(tile[cl][nl]));
    }
  } else {
    u16* o = hT + ((size_t)b*4096 + (size_t)nt*64) * 512 + ct*64;
    #pragma unroll
    for (int i = 0; i < 16; ++i) {
      int idx = i*256 + t; int nl = idx >> 6, cl = idx & 63;
      o[(size_t)nl*512 + cl] = tile[cl][nl];
    }
  }
}

// Cast weights: bf16 always (fallback), fp8 when useF8.
__global__ __launch_bounds__(256) void cast_w_k(const float* __restrict__ wq,
                                                const float* __restrict__ wp,
                                                u16* __restrict__ wqb,
                                                u16* __restrict__ wpb,
                                                u8* __restrict__ wq8,
                                                u8* __restrict__ wp8, int useF8) {
  int i = blockIdx.x*256 + threadIdx.x;
  if (useF8) {
    if (i < 1536*512) wq8[i] = f2e4m3(wq[i]);
    if (i < 512*512)  wp8[i] = f2e4m3(wp[i]);
  } else {
    if (i < 1536*512) wqb[i] = f2bf(wq[i]);
    if (i < 512*512)  wpb[i] = f2bf(wp[i]);
  }
}

// ---------------- NT GEMM core (m97 structure, 128x128, 4 waves, bf16) ----------
DEVINL void gemm_nt_core(const u16* __restrict__ A, int lda,
                         const u16* __restrict__ B, int ldb,
                         int K, u16* As, u16* Bs, f32x4 acc[4][4]) {
  const int tid = threadIdx.x;
  const int lane = tid & 63, w = tid >> 6;
  const int wr = w >> 1, wc = w & 1;
  const int fr = lane & 15, fk = lane >> 4;
  for (int kt = 0; kt < K; kt += 64) {
    #pragma unroll
    for (int i = 0; i < 4; ++i) {
      int ch = i*256 + tid;
      int row = ch >> 3, kc = ch & 7;
      gload16(A + (size_t)row*lda + kt + kc*8, As + ch*8);
      gload16(B + (size_t)row*ldb + kt + kc*8, Bs + ch*8);
    }
    __syncthreads();
    #pragma unroll
    for (int kk = 0; kk < 2; ++kk) {
      bf16x8 af[4], bfg[4];
      #pragma unroll
      for (int i = 0; i < 4; ++i)
        af[i] = *(const bf16x8*)(As + ((wr*64 + i*16 + fr)*64 + kk*32 + fk*8));
      #pragma unroll
      for (int j = 0; j < 4; ++j)
        bfg[j] = *(const bf16x8*)(Bs + ((wc*64 + j*16 + fr)*64 + kk*32 + fk*8));
      #pragma unroll
      for (int i = 0; i < 4; ++i)
        #pragma unroll
        for (int j = 0; j < 4; ++j)
          acc[i][j] = __builtin_amdgcn_mfma_f32_16x16x32_bf16(af[i], bfg[j], acc[i][j], 0, 0, 0);
    }
    __syncthreads();
  }
}

#define GEMM_PROLOGUE() \
  __shared__ __align__(16) u16 As[128*64]; \
  __shared__ __align__(16) u16 Bs[128*64]; \
  f32x4 acc[4][4] = {}; \
  const int tid = threadIdx.x; \
  const int lane = tid & 63, w = tid >> 6; \
  const int wr = w >> 1, wc = w & 1; \
  const int fr = lane & 15, fk = lane >> 4; \
  (void)lane;

// ---------------- NT GEMM fp8 core (BK=128, 4 waves; QKV/PROJ) ------------------
#define MFMA8(a, b, c) __builtin_amdgcn_mfma_f32_16x16x32_fp8_fp8((a), (b), (c), 0, 0, 0)

DEVINL void gemm_nt_f8(const u8* __restrict__ A, int lda,
                       const u8* __restrict__ B, int ldb,
                       int K, u8* Af, u8* Bf, f32x4 acc[4][4]) {
  const int tid = threadIdx.x;
  const int lane = tid & 63, w = tid >> 6;
  const int wr = w >> 1, wc = w & 1;
  const int fr = lane & 15, fk = lane >> 4;
  for (int kt = 0; kt < K; kt += 128) {
    #pragma unroll
    for (int q = 0; q < 4; ++q) {
      int c = q*256 + tid;                  // 1024 chunks of 16B per plane
      int row = c >> 3, s16 = c & 7;
      int kc = s16 ^ ((row >> 1) & 7);
      gload16b(A + (size_t)row*lda + kt + kc*16, Af + c*16);
      gload16b(B + (size_t)row*ldb + kt + kc*16, Bf + c*16);
    }
    __syncthreads();
    #pragma unroll
    for (int kk = 0; kk < 4; ++kk) {
      long long a8[4], b8[4];
      #pragma unroll
      for (int i = 0; i < 4; ++i) {
        int row = wr*64 + i*16 + fr;
        int s16r = (kk*2 + (fk>>1)) ^ ((row>>1)&7);
        a8[i] = *(const long long*)(Af + row*128 + (s16r<<4) + ((fk&1)<<3));
      }
      #pragma unroll
      for (int j = 0; j < 4; ++j) {
        int row = wc*64 + j*16 + fr;
        int s16r = (kk*2 + (fk>>1)) ^ ((row>>1)&7);
        b8[j] = *(const long long*)(Bf + row*128 + (s16r<<4) + ((fk&1)<<3));
      }
      #pragma unroll
      for (int i = 0; i < 4; ++i)
        #pragma unroll
        for (int j = 0; j < 4; ++j)
          acc[i][j] = MFMA8(a8[i], b8[j], acc[i][j]);
    }
    __syncthreads();
  }
}

// QKV bf16 (fallback path only).
__global__ __launch_bounds__(256) void k_qkv(const u16* __restrict__ hT,
                                             const u16* __restrict__ wq,
                                             const float* __restrict__ bqkv,
                                             u16* __restrict__ qT, u16* __restrict__ kT,
                                             u16* __restrict__ vb) {
  GEMM_PROLOGUE();
  const int bz = blockIdx.z;
  const int rowBase = blockIdx.y * 128, colBase = blockIdx.x * 128;
  gemm_nt_core(hT + ((size_t)bz*4096 + rowBase)*512, 512,
               wq + (size_t)colBase*512, 512, 512, As, Bs, acc);
  #pragma unroll
  for (int i = 0; i < 4; ++i)
    #pragma unroll
    for (int j = 0; j < 4; ++j)
      #pragma unroll
      for (int r = 0; r < 4; ++r) {
        int n = rowBase + wr*64 + i*16 + fk*4 + r;
        int o = colBase + wc*64 + j*16 + fr;
        u16 u = f2bf(acc[i][j][r] + bqkv[o]);
        if (o < 512)       qT[((size_t)bz*4096 + n)*512 + o]          = u;
        else if (o < 1024) kT[((size_t)bz*4096 + n)*512 + (o - 512)]  = u;
        else               vb[((size_t)bz*512 + (o - 1024))*4096 + n] = u;
      }
}

// QKV fp8: 4-wave BK=128 core, K=512 = 4 iterations.
__global__ __launch_bounds__(256) void k_qkv_f8(const u8* __restrict__ hT8,
                                                const u8* __restrict__ wq8,
                                                const float* __restrict__ bqkv,
                                                u8* __restrict__ qF8, u8* __restrict__ kF8,
                                                u8* __restrict__ vF8) {
  __shared__ __align__(16) u8 Af[128*128];   // 16 KB
  __shared__ __align__(16) u8 Bf[128*128];   // 16 KB
  f32x4 acc[4][4] = {};
  const int tid = threadIdx.x;
  const int lane = tid & 63, w = tid >> 6;
  const int wr = w >> 1, wc = w & 1;
  const int fr = lane & 15, fk = lane >> 4;
  const int bz = blockIdx.z;
  const int rowBase = blockIdx.y * 128, colBase = blockIdx.x * 128;
  gemm_nt_f8(hT8 + ((size_t)bz*4096 + rowBase)*512, 512,
             wq8 + (size_t)colBase*512, 512, 512, Af, Bf, acc);
  #pragma unroll
  for (int i = 0; i < 4; ++i)
    #pragma unroll
    for (int j = 0; j < 4; ++j)
      #pragma unroll
      for (int r = 0; r < 4; ++r) {
        int n = rowBase + wr*64 + i*16 + fk*4 + r;
        int o = colBase + wc*64 + j*16 + fr;
        u8 u = f2e4m3(acc[i][j][r] + bqkv[o]);
        if (o < 512)       qF8[((size_t)bz*4096 + n)*512 + o]          = u;
        else if (o < 1024) kF8[((size_t)bz*4096 + n)*512 + (o - 512)]  = u;
        else               vF8[((size_t)bz*512 + (o - 1024))*4096 + n] = u;
      }
}

// ------------- Scores (fp8): r23-best — single-buffer, E write only -------------
__global__ __launch_bounds__(512) void k_scores_f8(const u8* __restrict__ qF8,
                                                   const u8* __restrict__ kF8,
                                                   u8* __restrict__ E8) {
  __shared__ __align__(16) u8 Af[128*64];   // 8 KB
  __shared__ __align__(16) u8 Bf[128*64];   // 8 KB
  f32x4 acc[2][4] = {};
  const int tid = threadIdx.x;
  const int lane = tid & 63, w = tid >> 6;
  const int wr = w >> 1, wc = w & 1;        // 4M x 2N wave grid
  const int fr = lane & 15, fk = lane >> 4;
  const int bz = blockIdx.z;
  // T1: bijective XCD swizzle, 1024 blocks/slice (1024%8==0).
  int f = blockIdx.y * 32 + blockIdx.x;
  int L = (f & 7) * 128 + (f >> 3);
  const int rowBase = (L >> 5) * 128, colBase = (L & 31) * 128;
  const u8* qa = qF8 + (size_t)bz*4096*512 + (size_t)rowBase*512;
  const u8* ka = kF8 + (size_t)bz*4096*512 + (size_t)colBase*512;
  u8* Eb = E8 + (size_t)bz*4096*4096;

  for (int kt = 0; kt < 512; kt += 64) {
    {                                        // A,B: 512 chunks each, 1/thread
      int c = tid;
      int row = c >> 2, s16 = c & 3;
      int kc = s16 ^ ((row >> 1) & 3);       // inverse swizzle on global source
      gload16b(qa + (size_t)row*512 + kt + kc*16, Af + c*16);
      gload16b(ka + (size_t)row*512 + kt + kc*16, Bf + c*16);
    }
    __syncthreads();
    #pragma unroll
    for (int kk = 0; kk < 2; ++kk) {
      long long a8[2], b8[4];
      #pragma unroll
      for (int i = 0; i < 2; ++i) {
        int row = wr*32 + i*16 + fr;
        a8[i] = *(const long long*)(Af + row*64 +
                ((((kk*2 + (fk>>1)) ^ ((row>>1)&3)) << 4) | ((fk&1) << 3)));
      }
      #pragma unroll
      for (int j = 0; j < 4; ++j) {
        int row = wc*64 + j*16 + fr;
        b8[j] = *(const long long*)(Bf + row*64 +
                ((((kk*2 + (fk>>1)) ^ ((row>>1)&3)) << 4) | ((fk&1) << 3)));
      }
      #pragma unroll
      for (int i = 0; i < 2; ++i)
        #pragma unroll
        for (int j = 0; j < 4; ++j)
          acc[i][j] = MFMA8(a8[i], b8[j], acc[i][j]);
    }
    __syncthreads();
  }

  const float scale = 0.04419417382415922f;  // 512^-0.5
  #pragma unroll
  for (int i = 0; i < 2; ++i)
    #pragma unroll
    for (int r = 0; r < 4; ++r) {
      int nl = rowBase + wr*32 + i*16 + fk*4 + r;
      #pragma unroll
      for (int j = 0; j < 4; ++j) {
        int m = colBase + wc*64 + j*16 + fr;
        Eb[(size_t)nl*4096 + m] = f2e4m3(__expf(acc[i][j][r] * scale));
      }
    }
}

// ------------- PV (fp8): r23-best — 8 waves, lsum fused via ones-matrix MFMA ----
__global__ __launch_bounds__(512) void k_pv_f8(const u8* __restrict__ E8,
                                               const u8* __restrict__ vF8,
                                               u8* __restrict__ attn8) {
  __shared__ __align__(16) u8 Af[128*128];   // 16 KB
  __shared__ __align__(16) u8 Bf[128*128];   // 16 KB
  f32x4 acc[2][4] = {};
  f32x4 acs[2] = {};                          // row-sum accumulators
  const long long ONES = 0x3838383838383838LL;  // 8x fp8 e4m3 1.0
  const int tid = threadIdx.x;
  const int lane = tid & 63, w = tid >> 6;
  const int wr = w >> 1, wc = w & 1;          // 4M x 2N wave grid
  const int fr = lane & 15, fk = lane >> 4;
  const int bz = blockIdx.z;
  // T1: bijective XCD swizzle, 128 blocks/slice, grouped by E-row.
  int f = blockIdx.y * 4 + blockIdx.x;
  int L = (f & 7) * 16 + (f >> 3);
  const int rowBase = (L >> 2) * 128, colBase = (L & 3) * 128;
  const u8* Eb = E8 + (size_t)bz*4096*4096 + (size_t)rowBase*4096;
  const u8* vbb = vF8 + (size_t)bz*512*4096 + (size_t)colBase*4096;
  u8* ab = attn8 + (size_t)bz*4096*512;

  for (int kt = 0; kt < 4096; kt += 128) {
    #pragma unroll
    for (int q = 0; q < 2; ++q) {
      int c = q*512 + tid;                   // 1024 chunks of 16B per plane
      int row = c >> 3, s16 = c & 7;
      int kc = s16 ^ ((row >> 1) & 7);
      gload16b(Eb + (size_t)row*4096 + kt + kc*16, Af + c*16);
      gload16b(vbb + (size_t)row*4096 + kt + kc*16, Bf + c*16);
    }
    __syncthreads();
    #pragma unroll
    for (int kk = 0; kk < 4; ++kk) {
      long long a8[2], b8[4];
      #pragma unroll
      for (int i = 0; i < 2; ++i) {
        int row = wr*32 + i*16 + fr;
        int s16r = (kk*2 + (fk>>1)) ^ ((row>>1)&7);
        a8[i] = *(const long long*)(Af + row*128 + (s16r<<4) + ((fk&1)<<3));
      }
      #pragma unroll
      for (int j = 0; j < 4; ++j) {
        int row = wc*64 + j*16 + fr;
        int s16r = (kk*2 + (fk>>1)) ^ ((row>>1)&7);
        b8[j] = *(const long long*)(Bf + row*128 + (s16r<<4) + ((fk&1)<<3));
      }
      #pragma unroll
      for (int i = 0; i < 2; ++i) {
        #pragma unroll
        for (int j = 0; j < 4; ++j)
          acc[i][j] = MFMA8(a8[i], b8[j], acc[i][j]);
        acs[i] = MFMA8(a8[i], ONES, acs[i]);   // row-sum (all B cols = 1.0)
      }
    }
    __syncthreads();
  }

  #pragma unroll
  for (int i = 0; i < 2; ++i)
    #pragma unroll
    for (int r = 0; r < 4; ++r) {
      int nl = rowBase + wr*32 + i*16 + fk*4 + r;
      float rinv = 1.0f / acs[i][r];
      #pragma unroll
      for (int j = 0; j < 4; ++j) {
        int d = colBase + wc*64 + j*16 + fr;
        ab[(size_t)nl*512 + d] = f2e4m3(acc[i][j][r] * rinv);
      }
    }
}

// ------------- Proj (fp8): 4-wave BK=128 core; out = wp8.attn8 + bias + x -------
__global__ __launch_bounds__(256) void k_proj_f8(const u8* __restrict__ wp8,
                                                 const u8* __restrict__ attn8,
                                                 const float* __restrict__ bproj,
                                                 const float* __restrict__ x,
                                                 float* __restrict__ out) {
  __shared__ __align__(16) u8 Af[128*128];   // 16 KB
  __shared__ __align__(16) u8 Bf[128*128];   // 16 KB
  f32x4 acc[4][4] = {};
  const int tid = threadIdx.x;
  const int lane = tid & 63, w = tid >> 6;
  const int wr = w >> 1, wc = w & 1;
  const int fr = lane & 15, fk = lane >> 4;
  const int bz = blockIdx.z;
  const int rowBase = blockIdx.y * 128, colBase = blockIdx.x * 128;
  gemm_nt_f8(wp8 + (size_t)rowBase*512, 512,
             attn8 + ((size_t)bz*4096 + colBase)*512, 512, 512, Af, Bf, acc);
  #pragma unroll
  for (int i = 0; i < 4; ++i)
    #pragma unroll
    for (int j = 0; j < 4; ++j)
      #pragma unroll
      for (int r = 0; r < 4; ++r) {
        int o = rowBase + wr*64 + i*16 + fk*4 + r;
        int n = colBase + wc*64 + j*16 + fr;
        size_t idx = ((size_t)bz*512 + o)*4096 + n;
        out[idx] = acc[i][j][r] + bproj[o] + x[idx];
      }
}

// ---- bf16 fallback kernels (chunked path) --------------------------------------
__global__ __launch_bounds__(256) void k_scores(const u16* __restrict__ qT,
                                                const u16* __restrict__ kT,
                                                u16* __restrict__ E,
                                                float* __restrict__ lsum,
                                                long long qkStride, long long eStride,
                                                int lsStride) {
  GEMM_PROLOGUE();
  const int bz = blockIdx.z;
  const u16* q0 = qT + (size_t)bz * qkStride;
  const u16* k0 = kT + (size_t)bz * qkStride;
  u16* Eb = E + (size_t)bz * eStride;
  float* ls = lsum + (size_t)bz * lsStride;
  const int rowBase = blockIdx.y * 128, colBase = blockIdx.x * 128;
  gemm_nt_core(q0 + (size_t)rowBase*512, 512, k0 + (size_t)colBase*512, 512,
               512, As, Bs, acc);
  const float scale = 0.04419417382415922f;
  #pragma unroll
  for (int i = 0; i < 4; ++i)
    #pragma unroll
    for (int r = 0; r < 4; ++r) {
      int nl = rowBase + wr*64 + i*16 + fk*4 + r;
      float s = 0.f;
      #pragma unroll
      for (int j = 0; j < 4; ++j) {
        int m = colBase + wc*64 + j*16 + fr;
        float e = __expf(acc[i][j][r] * scale);
        Eb[(size_t)nl*4096 + m] = f2bf(e);
        s += e;
      }
      s += __shfl_xor(s, 1, 64);
      s += __shfl_xor(s, 2, 64);
      s += __shfl_xor(s, 4, 64);
      s += __shfl_xor(s, 8, 64);
      if (fr == 0) atomicAdd(&ls[nl], s);
    }
}

__global__ __launch_bounds__(256) void k_pv(const u16* __restrict__ E,
                                            const u16* __restrict__ vb,
                                            const float* __restrict__ lsum,
                                            u16* __restrict__ attnb,
                                            long long eStride, long long vStride,
                                            int lsStride, long long aStride) {
  GEMM_PROLOGUE();
  const int bz = blockIdx.z;
  const u16* Eb = E + (size_t)bz * eStride;
  const u16* vbb = vb + (size_t)bz * vStride;
  const float* ls = lsum + (size_t)bz * lsStride;
  u16* ab = attnb + (size_t)bz * aStride;
  const int rowBase = blockIdx.y * 128, colBase = blockIdx.x * 128;
  gemm_nt_core(Eb + (size_t)rowBase*4096, 4096, vbb + (size_t)colBase*4096, 4096,
               4096, As, Bs, acc);
  #pragma unroll
  for (int i = 0; i < 4; ++i)
    #pragma unroll
    for (int r = 0; r < 4; ++r) {
      int nl = rowBase + wr*64 + i*16 + fk*4 + r;
      float rinv = 1.0f / ls[nl];
      #pragma unroll
      for (int j = 0; j < 4; ++j) {
        int d = colBase + wc*64 + j*16 + fr;
        ab[(size_t)nl*512 + d] = f2bf(acc[i][j][r] * rinv);
      }
    }
}

__global__ __launch_bounds__(256) void k_proj(const u16* __restrict__ wp,
                                              const u16* __restrict__ attn,
                                              const float* __restrict__ bproj,
                                              const float* __restrict__ x,
                                              float* __restrict__ out) {
  GEMM_PROLOGUE();
  const int bz = blockIdx.z;
  const int rowBase = blockIdx.y * 128, colBase = blockIdx.x * 128;
  gemm_nt_core(wp + (size_t)rowBase*512, 512,
               attn + ((size_t)bz*4096 + colBase)*512, 512, 512, As, Bs, acc);
  #pragma unroll
  for (int i = 0; i < 4; ++i)
    #pragma unroll
    for (int j = 0; j < 4; ++j)
      #pragma unroll
      for (int r = 0; r < 4; ++r) {
        int o = rowBase + wr*64 + i*16 + fk*4 + r;
        int n = colBase + wc*64 + j*16 + fr;
        size_t idx = ((size_t)bz*512 + o)*4096 + n;
        out[idx] = acc[i][j][r] + bproj[o] + x[idx];
      }
}

extern "C" void kernel_launch(void* const* d_in, const int* in_sizes, int n_in,
                              void* d_out, int out_size, void* d_ws, size_t ws_size,
                              hipStream_t stream) {
  const float* x      = (const float*)d_in[0];
  const float* gamma  = (const float*)d_in[1];
  const float* beta   = (const float*)d_in[2];
  const float* w_qkv  = (const float*)d_in[3];
  const float* b_qkv  = (const float*)d_in[4];
  const float* w_proj = (const float*)d_in[5];
  const float* b_proj = (const float*)d_in[6];
  float* out = (float*)d_out;
  char* ws = (char*)d_ws;

  size_t off = 0;
  u16* wqb   = (u16*)(ws + off); off += (size_t)1536*512*2;
  u16* wpb   = (u16*)(ws + off); off += (size_t)512*512*2;
  u8*  wq8   = (u8*)(ws + off);  off += (size_t)1536*512;
  u8*  wp8   = (u8*)(ws + off);  off += (size_t)512*512;
  float* stats = (float*)(ws + off); off += 256;
  float* psum  = (float*)(ws + off); off += 512*4;
  float* psumsq= (float*)(ws + off); off += 512*4;
  float* lsum  = (float*)(ws + off); off += (size_t)4*4096*4;
  u16* hT    = (u16*)(ws + off);                      // reused as attn after QKV
  u16* attn  = hT;
  off += (size_t)4*4096*512*2;
  u16* qT    = (u16*)(ws + off); off += (size_t)4*4096*512*2;
  u16* kT    = (u16*)(ws + off); off += (size_t)4*4096*512*2;
  u16* vb    = (u16*)(ws + off); off += (size_t)4*4096*512*2;
  u16* E     = (u16*)(ws + off);
  size_t avail = ws_size > off ? ws_size - off : 0;
  const int useF8 = (avail >= (size_t)4*4096*4096) ? 1 : 0;   // fp8 E needs 67 MB
  // fp8 overlays of the bf16 buffers (exclusive use per path)
  u8* hT8  = (u8*)hT;
  u8* attn8 = hT8;
  u8* qF8 = (u8*)qT;
  u8* kF8 = (u8*)kT;
  u8* vF8 = (u8*)vb;
  u8* E8  = (u8*)E;

  gn_stats1_k<<<512, 256, 0, stream>>>(x, psum, psumsq);
  gn_stats2_k<<<1, 32, 0, stream>>>(psum, psumsq, stats);
  gn_apply_k<<<dim3(64, 8, 4), 256, 0, stream>>>(x, gamma, beta, stats, hT, hT8, useF8);
  cast_w_k<<<3072, 256, 0, stream>>>(w_qkv, w_proj, wqb, wpb, wq8, wp8, useF8);

  if (useF8) {
    k_qkv_f8<<<dim3(12, 32, 4), 256, 0, stream>>>(hT8, wq8, b_qkv, qF8, kF8, vF8);
    k_scores_f8<<<dim3(32, 32, 4), 512, 0, stream>>>(qF8, kF8, E8);
    k_pv_f8<<<dim3(4, 32, 4), 512, 0, stream>>>(E8, vF8, attn8);
    k_proj_f8<<<dim3(32, 4, 4), 256, 0, stream>>>(wp8, attn8, b_proj, x, out);
  } else {
    k_qkv<<<dim3(12, 32, 4), 256, 0, stream>>>(hT, wqb, b_qkv, qT, kT, vb);
    int CH = 4096;
    while (CH > 128 && (size_t)CH*4096*2 > avail) CH >>= 1;
    for (int b = 0; b < 4; ++b) {
      for (int c0 = 0; c0 < 4096; c0 += CH) {
        (void)hipMemsetAsync(lsum, 0, (size_t)CH * sizeof(float), stream);
        k_scores<<<dim3(32, CH/128, 1), 256, 0, stream>>>(
            qT + ((size_t)b*4096 + c0)*512, kT + (size_t)b*4096*512, E, lsum, 0, 0, 0);
        k_pv<<<dim3(4, CH/128, 1), 256, 0, stream>>>(
            E, vb + (size_t)b*512*4096, lsum, attn + ((size_t)b*4096 + c0)*512, 0, 0, 0, 0);
      }
    }
    k_proj<<<dim3(32, 4, 4), 256, 0, stream>>>(wpb, attn, b_proj, x, out);
  }
}

// Round 26
// 213.336 us; speedup vs baseline: 1.0086x; 1.0086x over previous
//
#include <hip/hip_runtime.h>

typedef __attribute__((ext_vector_type(8))) short bf16x8;
typedef __attribute__((ext_vector_type(4))) float f32x4;
typedef __attribute__((ext_vector_type(4))) short s16x4;
using u16 = unsigned short;
using u8 = unsigned char;
using u32 = unsigned int;

#define DEVINL static __device__ __forceinline__

DEVINL u16 f2bf(float f) {
  union { float f; unsigned u; } v; v.f = f;
  unsigned r = v.u + 0x7FFFu + ((v.u >> 16) & 1u);   // RNE
  return (u16)(r >> 16);
}

// fp32 -> OCP e4m3fn. Software fallback (RNE, saturating, denormal-aware).
DEVINL u8 f2e4m3_sw(float f) {
  union { float f; unsigned u; } v; v.f = f;
  unsigned s = (v.u >> 24) & 0x80u;
  float a = fabsf(f);
  a = fminf(a, 448.f);
  union { float f; unsigned u; } b; b.f = a;
  unsigned bu = b.u + 0x7FFFFu + ((b.u >> 20) & 1u);   // RNE at bit 20
  unsigned e = bu >> 23;
  unsigned r;
  if (e >= 121) {
    r = ((e - 120) << 3) | ((bu >> 20) & 7u);
    if (r > 0x7Eu) r = 0x7Eu;
  } else {
    r = (unsigned)(a * 512.f + 0.5f);
    if (r > 7u) r = 8u;
  }
  return (u8)(r | s);
}

#if __has_builtin(__builtin_amdgcn_cvt_pk_fp8_f32)
DEVINL u8 f2e4m3(float f) {
  int p = __builtin_amdgcn_cvt_pk_fp8_f32(f, f, 0, false);
  return (u8)(p & 0xFF);
}
#else
DEVINL u8 f2e4m3(float f) { return f2e4m3_sw(f); }
#endif

DEVINL float bf2f(u16 h) {
  union { unsigned u; float f; } v; v.u = ((unsigned)h) << 16; return v.f;
}

DEVINL void gload16(const u16* g, u16* l) {
  __builtin_amdgcn_global_load_lds((const __attribute__((address_space(1))) void*)g,
                                   (__attribute__((address_space(3))) void*)l,
                                   16, 0, 0);
}
DEVINL void gload16b(const u8* g, u8* l) {
  __builtin_amdgcn_global_load_lds((const __attribute__((address_space(1))) void*)g,
                                   (__attribute__((address_space(3))) void*)l,
                                   16, 0, 0);
}

// ------ GroupNorm stats stage 1 + fused weight cast (one dispatch saved) --------
__global__ __launch_bounds__(256) void gn_stats1_k(const float* __restrict__ x,
                                                   float* __restrict__ psum,
                                                   float* __restrict__ psumsq,
                                                   const float* __restrict__ wq,
                                                   const float* __restrict__ wp,
                                                   u16* __restrict__ wqb,
                                                   u16* __restrict__ wpb,
                                                   u8* __restrict__ wq8,
                                                   u8* __restrict__ wp8, int useF8) {
  const int blk = blockIdx.x;
  const float4* p4 = (const float4*)(x + (size_t)(blk >> 4) * (64 * 4096))
                     + (size_t)(blk & 15) * 4096;
  float s = 0.f, ss = 0.f;
  #pragma unroll
  for (int i = 0; i < 16; ++i) {
    float4 v = p4[i*256 + threadIdx.x];
    s  += v.x + v.y + v.z + v.w;
    ss += v.x*v.x + v.y*v.y + v.z*v.z + v.w*v.w;
  }
  #pragma unroll
  for (int off = 32; off > 0; off >>= 1) {
    s  += __shfl_down(s, off, 64);
    ss += __shfl_down(ss, off, 64);
  }
  __shared__ float rs[4], rss[4];
  const int lane = threadIdx.x & 63, w = threadIdx.x >> 6;
  if (lane == 0) { rs[w] = s; rss[w] = ss; }
  __syncthreads();
  if (threadIdx.x == 0) {
    psum[blk]   = rs[0]+rs[1]+rs[2]+rs[3];
    psumsq[blk] = rss[0]+rss[1]+rss[2]+rss[3];
  }
  // fused weight cast: 1,048,576 elements over 512x256 threads = 8 per thread
  const int NW1 = 1536*512, NW2 = 512*512, STR = 512*256;
  for (int i = blk*256 + threadIdx.x; i < NW1 + NW2; i += STR) {
    if (useF8) {
      if (i < NW1) wq8[i] = f2e4m3(wq[i]);
      else         wp8[i - NW1] = f2e4m3(wp[i - NW1]);
    } else {
      if (i < NW1) wqb[i] = f2bf(wq[i]);
      else         wpb[i - NW1] = f2bf(wp[i - NW1]);
    }
  }
}

// Normalize + transpose with inline stats finalize (gn_stats2 folded in).
// x[b][c][n] -> hT[b][n][c]; fp8 (packed u32 stores) when useF8, else bf16.
__global__ __launch_bounds__(256) void gn_apply_k(const float* __restrict__ x,
                                                  const float* __restrict__ gamma,
                                                  const float* __restrict__ beta,
                                                  const float* __restrict__ psum,
                                                  const float* __restrict__ psumsq,
                                                  u16* __restrict__ hT,
                                                  u8* __restrict__ hT8, int useF8) {
  __shared__ u16 tile[64][68];
  const int b = blockIdx.z, ct = blockIdx.y, nt = blockIdx.x;
  const int t = threadIdx.x;
  // inline stats finalize (same summation order as the old gn_stats2_k)
  const int g = b*8 + ct;
  float s = 0.f, ss = 0.f;
  #pragma unroll
  for (int p = 0; p < 16; ++p) { s += psum[g*16+p]; ss += psumsq[g*16+p]; }
  const float inv = 1.f / 262144.f;
  const float mean = s * inv;
  const float rstd = rsqrtf(ss * inv - mean * mean + 1e-5f);
  const float* xb = x + ((size_t)b*512 + (size_t)ct*64) * 4096 + nt*64;
  #pragma unroll
  for (int i = 0; i < 4; ++i) {
    int idx = i*256 + t;                 // 1024 float4 loads cover 64x64
    int cl = idx >> 4, nl4 = idx & 15;
    float4 v = *(const float4*)(xb + (size_t)cl*4096 + nl4*4);
    float gg = gamma[ct*64 + cl], bb = beta[ct*64 + cl];
    s16x4 o;
    o.x = (short)f2bf((v.x - mean) * rstd * gg + bb);
    o.y = (short)f2bf((v.y - mean) * rstd * gg + bb);
    o.z = (short)f2bf((v.z - mean) * rstd * gg + bb);
    o.w = (short)f2bf((v.w - mean) * rstd * gg + bb);
    *(s16x4*)(&tile[cl][nl4*4]) = o;
  }
  __syncthreads();
  if (useF8) {
    u8* o = hT8 + ((size_t)b*4096 + (size_t)nt*64) * 512 + ct*64;
    #pragma unroll
    for (int i = 0; i < 4; ++i) {        // packed 4B stores (G13 store side)
      int idx = i*256 + t; int nl = idx >> 4, c4 = (idx & 15) * 4;
      u32 pk = (u32)f2e4m3(bf2f(tile[c4+0][nl]))
             | ((u32)f2e4m3(bf2f(tile[c4+1][nl])) << 8)
             | ((u32)f2e4m3(bf2f(tile[c4+2][nl])) << 16)
             | ((u32)f2e4m3(bf2f(tile[c4+3][nl])) << 24);
      *(u32*)(o + (size_t)nl*512 + c4) = pk;
    }
  } else {
    u16* o = hT + ((size_t)b*4096 + (size_t)nt*64) * 512 + ct*64;
    #pragma unroll
    for (int i = 0; i < 16; ++i) {
      int idx = i*256 + t; int nl = idx >> 6, cl = idx & 63;
      o[(size_t)nl*512 + cl] = tile[cl][nl];
    }
  }
}

// ---------------- NT GEMM core (m97 structure, 128x128, 4 waves, bf16) ----------
DEVINL void gemm_nt_core(const u16* __restrict__ A, int lda,
                         const u16* __restrict__ B, int ldb,
                         int K, u16* As, u16* Bs, f32x4 acc[4][4]) {
  const int tid = threadIdx.x;
  const int lane = tid & 63, w = tid >> 6;
  const int wr = w >> 1, wc = w & 1;
  const int fr = lane & 15, fk = lane >> 4;
  for (int kt = 0; kt < K; kt += 64) {
    #pragma unroll
    for (int i = 0; i < 4; ++i) {
      int ch = i*256 + tid;
      int row = ch >> 3, kc = ch & 7;
      gload16(A + (size_t)row*lda + kt + kc*8, As + ch*8);
      gload16(B + (size_t)row*ldb + kt + kc*8, Bs + ch*8);
    }
    __syncthreads();
    #pragma unroll
    for (int kk = 0; kk < 2; ++kk) {
      bf16x8 af[4], bfg[4];
      #pragma unroll
      for (int i = 0; i < 4; ++i)
        af[i] = *(const bf16x8*)(As + ((wr*64 + i*16 + fr)*64 + kk*32 + fk*8));
      #pragma unroll
      for (int j = 0; j < 4; ++j)
        bfg[j] = *(const bf16x8*)(Bs + ((wc*64 + j*16 + fr)*64 + kk*32 + fk*8));
      #pragma unroll
      for (int i = 0; i < 4; ++i)
        #pragma unroll
        for (int j = 0; j < 4; ++j)
          acc[i][j] = __builtin_amdgcn_mfma_f32_16x16x32_bf16(af[i], bfg[j], acc[i][j], 0, 0, 0);
    }
    __syncthreads();
  }
}

#define GEMM_PROLOGUE() \
  __shared__ __align__(16) u16 As[128*64]; \
  __shared__ __align__(16) u16 Bs[128*64]; \
  f32x4 acc[4][4] = {}; \
  const int tid = threadIdx.x; \
  const int lane = tid & 63, w = tid >> 6; \
  const int wr = w >> 1, wc = w & 1; \
  const int fr = lane & 15, fk = lane >> 4; \
  (void)lane;

// ---------------- NT GEMM fp8 core (BK=128, 4 waves; QKV/PROJ) ------------------
#define MFMA8(a, b, c) __builtin_amdgcn_mfma_f32_16x16x32_fp8_fp8((a), (b), (c), 0, 0, 0)

DEVINL void gemm_nt_f8(const u8* __restrict__ A, int lda,
                       const u8* __restrict__ B, int ldb,
                       int K, u8* Af, u8* Bf, f32x4 acc[4][4]) {
  const int tid = threadIdx.x;
  const int lane = tid & 63, w = tid >> 6;
  const int wr = w >> 1, wc = w & 1;
  const int fr = lane & 15, fk = lane >> 4;
  for (int kt = 0; kt < K; kt += 128) {
    #pragma unroll
    for (int q = 0; q < 4; ++q) {
      int c = q*256 + tid;                  // 1024 chunks of 16B per plane
      int row = c >> 3, s16 = c & 7;
      int kc = s16 ^ ((row >> 1) & 7);
      gload16b(A + (size_t)row*lda + kt + kc*16, Af + c*16);
      gload16b(B + (size_t)row*ldb + kt + kc*16, Bf + c*16);
    }
    __syncthreads();
    #pragma unroll
    for (int kk = 0; kk < 4; ++kk) {
      long long a8[4], b8[4];
      #pragma unroll
      for (int i = 0; i < 4; ++i) {
        int row = wr*64 + i*16 + fr;
        int s16r = (kk*2 + (fk>>1)) ^ ((row>>1)&7);
        a8[i] = *(const long long*)(Af + row*128 + (s16r<<4) + ((fk&1)<<3));
      }
      #pragma unroll
      for (int j = 0; j < 4; ++j) {
        int row = wc*64 + j*16 + fr;
        int s16r = (kk*2 + (fk>>1)) ^ ((row>>1)&7);
        b8[j] = *(const long long*)(Bf + row*128 + (s16r<<4) + ((fk&1)<<3));
      }
      #pragma unroll
      for (int i = 0; i < 4; ++i)
        #pragma unroll
        for (int j = 0; j < 4; ++j)
          acc[i][j] = MFMA8(a8[i], b8[j], acc[i][j]);
    }
    __syncthreads();
  }
}

// QKV bf16 (fallback path only).
__global__ __launch_bounds__(256) void k_qkv(const u16* __restrict__ hT,
                                             const u16* __restrict__ wq,
                                             const float* __restrict__ bqkv,
                                             u16* __restrict__ qT, u16* __restrict__ kT,
                                             u16* __restrict__ vb) {
  GEMM_PROLOGUE();
  const int bz = blockIdx.z;
  const int rowBase = blockIdx.y * 128, colBase = blockIdx.x * 128;
  gemm_nt_core(hT + ((size_t)bz*4096 + rowBase)*512, 512,
               wq + (size_t)colBase*512, 512, 512, As, Bs, acc);
  #pragma unroll
  for (int i = 0; i < 4; ++i)
    #pragma unroll
    for (int j = 0; j < 4; ++j)
      #pragma unroll
      for (int r = 0; r < 4; ++r) {
        int n = rowBase + wr*64 + i*16 + fk*4 + r;
        int o = colBase + wc*64 + j*16 + fr;
        u16 u = f2bf(acc[i][j][r] + bqkv[o]);
        if (o < 512)       qT[((size_t)bz*4096 + n)*512 + o]          = u;
        else if (o < 1024) kT[((size_t)bz*4096 + n)*512 + (o - 512)]  = u;
        else               vb[((size_t)bz*512 + (o - 1024))*4096 + n] = u;
      }
}

// QKV fp8: 4-wave BK=128 core, K=512 = 4 iterations.
__global__ __launch_bounds__(256) void k_qkv_f8(const u8* __restrict__ hT8,
                                                const u8* __restrict__ wq8,
                                                const float* __restrict__ bqkv,
                                                u8* __restrict__ qF8, u8* __restrict__ kF8,
                                                u8* __restrict__ vF8) {
  __shared__ __align__(16) u8 Af[128*128];   // 16 KB
  __shared__ __align__(16) u8 Bf[128*128];   // 16 KB
  f32x4 acc[4][4] = {};
  const int tid = threadIdx.x;
  const int lane = tid & 63, w = tid >> 6;
  const int wr = w >> 1, wc = w & 1;
  const int fr = lane & 15, fk = lane >> 4;
  const int bz = blockIdx.z;
  const int rowBase = blockIdx.y * 128, colBase = blockIdx.x * 128;
  gemm_nt_f8(hT8 + ((size_t)bz*4096 + rowBase)*512, 512,
             wq8 + (size_t)colBase*512, 512, 512, Af, Bf, acc);
  #pragma unroll
  for (int i = 0; i < 4; ++i)
    #pragma unroll
    for (int j = 0; j < 4; ++j)
      #pragma unroll
      for (int r = 0; r < 4; ++r) {
        int n = rowBase + wr*64 + i*16 + fk*4 + r;
        int o = colBase + wc*64 + j*16 + fr;
        u8 u = f2e4m3(acc[i][j][r] + bqkv[o]);
        if (o < 512)       qF8[((size_t)bz*4096 + n)*512 + o]          = u;
        else if (o < 1024) kF8[((size_t)bz*4096 + n)*512 + (o - 512)]  = u;
        else               vF8[((size_t)bz*512 + (o - 1024))*4096 + n] = u;
      }
}

// ------------- Scores (fp8): r23-best — single-buffer, E write only -------------
__global__ __launch_bounds__(512) void k_scores_f8(const u8* __restrict__ qF8,
                                                   const u8* __restrict__ kF8,
                                                   u8* __restrict__ E8) {
  __shared__ __align__(16) u8 Af[128*64];   // 8 KB
  __shared__ __align__(16) u8 Bf[128*64];   // 8 KB
  f32x4 acc[2][4] = {};
  const int tid = threadIdx.x;
  const int lane = tid & 63, w = tid >> 6;
  const int wr = w >> 1, wc = w & 1;        // 4M x 2N wave grid
  const int fr = lane & 15, fk = lane >> 4;
  const int bz = blockIdx.z;
  // T1: bijective XCD swizzle, 1024 blocks/slice (1024%8==0).
  int f = blockIdx.y * 32 + blockIdx.x;
  int L = (f & 7) * 128 + (f >> 3);
  const int rowBase = (L >> 5) * 128, colBase = (L & 31) * 128;
  const u8* qa = qF8 + (size_t)bz*4096*512 + (size_t)rowBase*512;
  const u8* ka = kF8 + (size_t)bz*4096*512 + (size_t)colBase*512;
  u8* Eb = E8 + (size_t)bz*4096*4096;

  for (int kt = 0; kt < 512; kt += 64) {
    {                                        // A,B: 512 chunks each, 1/thread
      int c = tid;
      int row = c >> 2, s16 = c & 3;
      int kc = s16 ^ ((row >> 1) & 3);       // inverse swizzle on global source
      gload16b(qa + (size_t)row*512 + kt + kc*16, Af + c*16);
      gload16b(ka + (size_t)row*512 + kt + kc*16, Bf + c*16);
    }
    __syncthreads();
    #pragma unroll
    for (int kk = 0; kk < 2; ++kk) {
      long long a8[2], b8[4];
      #pragma unroll
      for (int i = 0; i < 2; ++i) {
        int row = wr*32 + i*16 + fr;
        a8[i] = *(const long long*)(Af + row*64 +
                ((((kk*2 + (fk>>1)) ^ ((row>>1)&3)) << 4) | ((fk&1) << 3)));
      }
      #pragma unroll
      for (int j = 0; j < 4; ++j) {
        int row = wc*64 + j*16 + fr;
        b8[j] = *(const long long*)(Bf + row*64 +
                ((((kk*2 + (fk>>1)) ^ ((row>>1)&3)) << 4) | ((fk&1) << 3)));
      }
      #pragma unroll
      for (int i = 0; i < 2; ++i)
        #pragma unroll
        for (int j = 0; j < 4; ++j)
          acc[i][j] = MFMA8(a8[i], b8[j], acc[i][j]);
    }
    __syncthreads();
  }

  const float scale = 0.04419417382415922f;  // 512^-0.5
  #pragma unroll
  for (int i = 0; i < 2; ++i)
    #pragma unroll
    for (int r = 0; r < 4; ++r) {
      int nl = rowBase + wr*32 + i*16 + fk*4 + r;
      #pragma unroll
      for (int j = 0; j < 4; ++j) {
        int m = colBase + wc*64 + j*16 + fr;
        Eb[(size_t)nl*4096 + m] = f2e4m3(__expf(acc[i][j][r] * scale));
      }
    }
}

// ------------- PV (fp8): r23-best — 8 waves, lsum fused via ones-matrix MFMA ----
__global__ __launch_bounds__(512) void k_pv_f8(const u8* __restrict__ E8,
                                               const u8* __restrict__ vF8,
                                               u8* __restrict__ attn8) {
  __shared__ __align__(16) u8 Af[128*128];   // 16 KB
  __shared__ __align__(16) u8 Bf[128*128];   // 16 KB
  f32x4 acc[2][4] = {};
  f32x4 acs[2] = {};                          // row-sum accumulators
  const long long ONES = 0x3838383838383838LL;  // 8x fp8 e4m3 1.0
  const int tid = threadIdx.x;
  const int lane = tid & 63, w = tid >> 6;
  const int wr = w >> 1, wc = w & 1;          // 4M x 2N wave grid
  const int fr = lane & 15, fk = lane >> 4;
  const int bz = blockIdx.z;
  // T1: bijective XCD swizzle, 128 blocks/slice, grouped by E-row.
  int f = blockIdx.y * 4 + blockIdx.x;
  int L = (f & 7) * 16 + (f >> 3);
  const int rowBase = (L >> 2) * 128, colBase = (L & 3) * 128;
  const u8* Eb = E8 + (size_t)bz*4096*4096 + (size_t)rowBase*4096;
  const u8* vbb = vF8 + (size_t)bz*512*4096 + (size_t)colBase*4096;
  u8* ab = attn8 + (size_t)bz*4096*512;

  for (int kt = 0; kt < 4096; kt += 128) {
    #pragma unroll
    for (int q = 0; q < 2; ++q) {
      int c = q*512 + tid;                   // 1024 chunks of 16B per plane
      int row = c >> 3, s16 = c & 7;
      int kc = s16 ^ ((row >> 1) & 7);
      gload16b(Eb + (size_t)row*4096 + kt + kc*16, Af + c*16);
      gload16b(vbb + (size_t)row*4096 + kt + kc*16, Bf + c*16);
    }
    __syncthreads();
    #pragma unroll
    for (int kk = 0; kk < 4; ++kk) {
      long long a8[2], b8[4];
      #pragma unroll
      for (int i = 0; i < 2; ++i) {
        int row = wr*32 + i*16 + fr;
        int s16r = (kk*2 + (fk>>1)) ^ ((row>>1)&7);
        a8[i] = *(const long long*)(Af + row*128 + (s16r<<4) + ((fk&1)<<3));
      }
      #pragma unroll
      for (int j = 0; j < 4; ++j) {
        int row = wc*64 + j*16 + fr;
        int s16r = (kk*2 + (fk>>1)) ^ ((row>>1)&7);
        b8[j] = *(const long long*)(Bf + row*128 + (s16r<<4) + ((fk&1)<<3));
      }
      #pragma unroll
      for (int i = 0; i < 2; ++i) {
        #pragma unroll
        for (int j = 0; j < 4; ++j)
          acc[i][j] = MFMA8(a8[i], b8[j], acc[i][j]);
        acs[i] = MFMA8(a8[i], ONES, acs[i]);   // row-sum (all B cols = 1.0)
      }
    }
    __syncthreads();
  }

  #pragma unroll
  for (int i = 0; i < 2; ++i)
    #pragma unroll
    for (int r = 0; r < 4; ++r) {
      int nl = rowBase + wr*32 + i*16 + fk*4 + r;
      float rinv = 1.0f / acs[i][r];
      #pragma unroll
      for (int j = 0; j < 4; ++j) {
        int d = colBase + wc*64 + j*16 + fr;
        ab[(size_t)nl*512 + d] = f2e4m3(acc[i][j][r] * rinv);
      }
    }
}

// ------------- Proj (fp8): 4-wave BK=128 core; out = wp8.attn8 + bias + x -------
__global__ __launch_bounds__(256) void k_proj_f8(const u8* __restrict__ wp8,
                                                 const u8* __restrict__ attn8,
                                                 const float* __restrict__ bproj,
                                                 const float* __restrict__ x,
                                                 float* __restrict__ out) {
  __shared__ __align__(16) u8 Af[128*128];   // 16 KB
  __shared__ __align__(16) u8 Bf[128*128];   // 16 KB
  f32x4 acc[4][4] = {};
  const int tid = threadIdx.x;
  const int lane = tid & 63, w = tid >> 6;
  const int wr = w >> 1, wc = w & 1;
  const int fr = lane & 15, fk = lane >> 4;
  const int bz = blockIdx.z;
  const int rowBase = blockIdx.y * 128, colBase = blockIdx.x * 128;
  gemm_nt_f8(wp8 + (size_t)rowBase*512, 512,
             attn8 + ((size_t)bz*4096 + colBase)*512, 512, 512, Af, Bf, acc);
  #pragma unroll
  for (int i = 0; i < 4; ++i)
    #pragma unroll
    for (int j = 0; j < 4; ++j)
      #pragma unroll
      for (int r = 0; r < 4; ++r) {
        int o = rowBase + wr*64 + i*16 + fk*4 + r;
        int n = colBase + wc*64 + j*16 + fr;
        size_t idx = ((size_t)bz*512 + o)*4096 + n;
        out[idx] = acc[i][j][r] + bproj[o] + x[idx];
      }
}

// ---- bf16 fallback kernels (chunked path) --------------------------------------
__global__ __launch_bounds__(256) void k_scores(const u16* __restrict__ qT,
                                                const u16* __restrict__ kT,
                                                u16* __restrict__ E,
                                                float* __restrict__ lsum,
                                                long long qkStride, long long eStride,
                                                int lsStride) {
  GEMM_PROLOGUE();
  const int bz = blockIdx.z;
  const u16* q0 = qT + (size_t)bz * qkStride;
  const u16* k0 = kT + (size_t)bz * qkStride;
  u16* Eb = E + (size_t)bz * eStride;
  float* ls = lsum + (size_t)bz * lsStride;
  const int rowBase = blockIdx.y * 128, colBase = blockIdx.x * 128;
  gemm_nt_core(q0 + (size_t)rowBase*512, 512, k0 + (size_t)colBase*512, 512,
               512, As, Bs, acc);
  const float scale = 0.04419417382415922f;
  #pragma unroll
  for (int i = 0; i < 4; ++i)
    #pragma unroll
    for (int r = 0; r < 4; ++r) {
      int nl = rowBase + wr*64 + i*16 + fk*4 + r;
      float s = 0.f;
      #pragma unroll
      for (int j = 0; j < 4; ++j) {
        int m = colBase + wc*64 + j*16 + fr;
        float e = __expf(acc[i][j][r] * scale);
        Eb[(size_t)nl*4096 + m] = f2bf(e);
        s += e;
      }
      s += __shfl_xor(s, 1, 64);
      s += __shfl_xor(s, 2, 64);
      s += __shfl_xor(s, 4, 64);
      s += __shfl_xor(s, 8, 64);
      if (fr == 0) atomicAdd(&ls[nl], s);
    }
}

__global__ __launch_bounds__(256) void k_pv(const u16* __restrict__ E,
                                            const u16* __restrict__ vb,
                                            const float* __restrict__ lsum,
                                            u16* __restrict__ attnb,
                                            long long eStride, long long vStride,
                                            int lsStride, long long aStride) {
  GEMM_PROLOGUE();
  const int bz = blockIdx.z;
  const u16* Eb = E + (size_t)bz * eStride;
  const u16* vbb = vb + (size_t)bz * vStride;
  const float* ls = lsum + (size_t)bz * lsStride;
  u16* ab = attnb + (size_t)bz * aStride;
  const int rowBase = blockIdx.y * 128, colBase = blockIdx.x * 128;
  gemm_nt_core(Eb + (size_t)rowBase*4096, 4096, vbb + (size_t)colBase*4096, 4096,
               4096, As, Bs, acc);
  #pragma unroll
  for (int i = 0; i < 4; ++i)
    #pragma unroll
    for (int r = 0; r < 4; ++r) {
      int nl = rowBase + wr*64 + i*16 + fk*4 + r;
      float rinv = 1.0f / ls[nl];
      #pragma unroll
      for (int j = 0; j < 4; ++j) {
        int d = colBase + wc*64 + j*16 + fr;
        ab[(size_t)nl*512 + d] = f2bf(acc[i][j][r] * rinv);
      }
    }
}

__global__ __launch_bounds__(256) void k_proj(const u16* __restrict__ wp,
                                              const u16* __restrict__ attn,
                                              const float* __restrict__ bproj,
                                              const float* __restrict__ x,
                                              float* __restrict__ out) {
  GEMM_PROLOGUE();
  const int bz = blockIdx.z;
  const int rowBase = blockIdx.y * 128, colBase = blockIdx.x * 128;
  gemm_nt_core(wp + (size_t)rowBase*512, 512,
               attn + ((size_t)bz*4096 + colBase)*512, 512, 512, As, Bs, acc);
  #pragma unroll
  for (int i = 0; i < 4; ++i)
    #pragma unroll
    for (int j = 0; j < 4; ++j)
      #pragma unroll
      for (int r = 0; r < 4; ++r) {
        int o = rowBase + wr*64 + i*16 + fk*4 + r;
        int n = colBase + wc*64 + j*16 + fr;
        size_t idx = ((size_t)bz*512 + o)*4096 + n;
        out[idx] = acc[i][j][r] + bproj[o] + x[idx];
      }
}

extern "C" void kernel_launch(void* const* d_in, const int* in_sizes, int n_in,
                              void* d_out, int out_size, void* d_ws, size_t ws_size,
                              hipStream_t stream) {
  const float* x      = (const float*)d_in[0];
  const float* gamma  = (const float*)d_in[1];
  const float* beta   = (const float*)d_in[2];
  const float* w_qkv  = (const float*)d_in[3];
  const float* b_qkv  = (const float*)d_in[4];
  const float* w_proj = (const float*)d_in[5];
  const float* b_proj = (const float*)d_in[6];
  float* out = (float*)d_out;
  char* ws = (char*)d_ws;

  size_t off = 0;
  u16* wqb   = (u16*)(ws + off); off += (size_t)1536*512*2;
  u16* wpb   = (u16*)(ws + off); off += (size_t)512*512*2;
  u8*  wq8   = (u8*)(ws + off);  off += (size_t)1536*512;
  u8*  wp8   = (u8*)(ws + off);  off += (size_t)512*512;
  float* psum  = (float*)(ws + off); off += 512*4;
  float* psumsq= (float*)(ws + off); off += 512*4;
  float* lsum  = (float*)(ws + off); off += (size_t)4*4096*4;
  u16* hT    = (u16*)(ws + off);                      // reused as attn after QKV
  u16* attn  = hT;
  off += (size_t)4*4096*512*2;
  u16* qT    = (u16*)(ws + off); off += (size_t)4*4096*512*2;
  u16* kT    = (u16*)(ws + off); off += (size_t)4*4096*512*2;
  u16* vb    = (u16*)(ws + off); off += (size_t)4*4096*512*2;
  u16* E     = (u16*)(ws + off);
  size_t avail = ws_size > off ? ws_size - off : 0;
  const int useF8 = (avail >= (size_t)4*4096*4096) ? 1 : 0;   // fp8 E needs 67 MB
  // fp8 overlays of the bf16 buffers (exclusive use per path)
  u8* hT8  = (u8*)hT;
  u8* attn8 = hT8;
  u8* qF8 = (u8*)qT;
  u8* kF8 = (u8*)kT;
  u8* vF8 = (u8*)vb;
  u8* E8  = (u8*)E;

  gn_stats1_k<<<512, 256, 0, stream>>>(x, psum, psumsq, w_qkv, w_proj,
                                       wqb, wpb, wq8, wp8, useF8);
  gn_apply_k<<<dim3(64, 8, 4), 256, 0, stream>>>(x, gamma, beta, psum, psumsq,
                                                 hT, hT8, useF8);

  if (useF8) {
    k_qkv_f8<<<dim3(12, 32, 4), 256, 0, stream>>>(hT8, wq8, b_qkv, qF8, kF8, vF8);
    k_scores_f8<<<dim3(32, 32, 4), 512, 0, stream>>>(qF8, kF8, E8);
    k_pv_f8<<<dim3(4, 32, 4), 512, 0, stream>>>(E8, vF8, attn8);
    k_proj_f8<<<dim3(32, 4, 4), 256, 0, stream>>>(wp8, attn8, b_proj, x, out);
  } else {
    k_qkv<<<dim3(12, 32, 4), 256, 0, stream>>>(hT, wqb, b_qkv, qT, kT, vb);
    int CH = 4096;
    while (CH > 128 && (size_t)CH*4096*2 > avail) CH >>= 1;
    for (int b = 0; b < 4; ++b) {
      for (int c0 = 0; c0 < 4096; c0 += CH) {
        (void)hipMemsetAsync(lsum, 0, (size_t)CH * sizeof(float), stream);
        k_scores<<<dim3(32, CH/128, 1), 256, 0, stream>>>(
            qT + ((size_t)b*4096 + c0)*512, kT + (size_t)b*4096*512, E, lsum, 0, 0, 0);
        k_pv<<<dim3(4, CH/128, 1), 256, 0, stream>>>(
            E, vb + (size_t)b*512*4096, lsum, attn + ((size_t)b*4096 + c0)*512, 0, 0, 0, 0);
      }
    }
    k_proj<<<dim3(32, 4, 4), 256, 0, stream>>>(wpb, attn, b_proj, x, out);
  }
}